// Round 8
// baseline (288.825 us; speedup 1.0000x reference)
//
#include <hip/hip_runtime.h>
#include <hip/hip_bf16.h>
#include <math.h>

#define T_TOK 8192
#define DM 1024
#define DE 512
#define NE 8
#define DFF 4096

// converted/derived bf16 buffer layout (element offsets inside conv)
#define CO_X   0
#define CO_W1  8388608   // w1T [8][512][1024]
#define CO_W2  12582912  // w2T [8][1024][512]
#define CO_B1  16777216
#define CO_B2  16781312
#define CO_CE  16789504
#define CO_WR  16797696

// workspace byte offsets
// meta ints: [0]=dtype flag, [16..23]=counts, [32..39]=expert bases
#define WS_GATE2 256
#define WS_B32   65792
#define WS_TOP2  262400
#define WS_TOK   295168
#define WS_AE    360704
#define WS_AG    426240
#define WS_INV   491776
#define WS_CONV  557312
#define WS_HC    34169088
#define WS_OC    50946304

typedef __attribute__((ext_vector_type(8))) __bf16 bf16x8;
typedef __attribute__((ext_vector_type(4))) __bf16 bf16x4;
typedef __attribute__((ext_vector_type(4))) float f32x4;

__device__ __forceinline__ f32x4 ld4(const void* p, size_t off, int md)
{
  f32x4 r;
  if (md){
    bf16x4 v = *(const bf16x4*)((const __bf16*)p + off);
    #pragma unroll
    for (int j = 0; j < 4; j++) r[j] = (float)v[j];
  } else {
    r = *(const f32x4*)((const float*)p + off);
  }
  return r;
}

// async 16B global -> LDS (dest must be lane-linear: base + lane*16)
__device__ __forceinline__ void async_ld16(const __bf16* g, __bf16* l)
{
  __builtin_amdgcn_global_load_lds(
      (const __attribute__((address_space(1))) unsigned int*)g,
      (__attribute__((address_space(3))) unsigned int*)l, 16, 0, 0);
}

// per-block dtype detection (reads first 4KB of x; L2-broadcast across blocks)
__device__ __forceinline__ int detect_md_block(const float* xf, int tid,
                                               int* cnt_lds)
{
  int ok = 0;
  #pragma unroll
  for (int i = 0; i < 4; i++){
    float a = fabsf(xf[tid + i * 256]);
    if (a > 1e-8f && a < 100.f) ok++;  // NaN compares false
  }
  if (tid == 0) *cnt_lds = 0;
  __syncthreads();
  atomicAdd(cnt_lds, ok);
  __syncthreads();
  return (*cnt_lds > 512) ? 0 : 1;
}

// ---- prep_k: fused transp (8192 blk) + convert (28 blk) + route (512 blk) --
// Single launch replaces detect/transp/convert/route: kills 3 launch
// overheads and lets transp blocks fill CUs idle during 512-block routing.
__global__ __launch_bounds__(256) void prep_k(
    const void* xp, const void* w1q, const void* w2q,
    const void* b1q, const void* b2q, const void* cp, const void* wp,
    __bf16* __restrict__ conv, int* __restrict__ meta,
    float2* __restrict__ gate2, int* __restrict__ top2, int* __restrict__ b32)
{
  __shared__ int mdcnt;
  __shared__ __bf16 tile[32][33];
  __shared__ int hist[8];
  __shared__ float cinvL[8];

  const int tid = threadIdx.x;
  const int md = detect_md_block((const float*)xp, tid, &mdcnt);
  const int b = blockIdx.x;

  if (b < 8192){
    // -------- transpose w1 -> w1T, w2 -> w2T --------
    const void* src; __bf16* dst; int ldS, ldD, i0, j0; size_t soff, doffb;
    const int ty = tid >> 5, tx = tid & 31;
    if (b < 4096){                       // w1[e]: [1024][512] -> [512][1024]
      const int e = b >> 9, t = b & 511;
      i0 = (t >> 4) << 5; j0 = (t & 15) << 5;
      ldS = DE; ldD = DM;
      soff = (size_t)e * DM * DE;
      dst = conv + CO_W1; doffb = (size_t)e * DE * DM;
      src = md ? (const void*)((const __bf16*)w1q) : (const void*)((const float*)w1q);
    } else {                             // w2[e]: [512][1024] -> [1024][512]
      const int e = (b - 4096) >> 9, t = (b - 4096) & 511;
      i0 = (t >> 5) << 5; j0 = (t & 31) << 5;
      ldS = DM; ldD = DE;
      soff = (size_t)e * DE * DM;
      dst = conv + CO_W2; doffb = (size_t)e * DM * DE;
      src = md ? (const void*)((const __bf16*)w2q) : (const void*)((const float*)w2q);
    }
    #pragma unroll
    for (int rr = 0; rr < 4; rr++){
      const int r = rr * 8 + ty;
      const size_t s = soff + (size_t)(i0 + r) * ldS + j0 + tx;
      tile[r][tx] = md ? ((const __bf16*)src)[s] : (__bf16)((const float*)src)[s];
    }
    __syncthreads();
    #pragma unroll
    for (int rr = 0; rr < 4; rr++){
      const int r = rr * 8 + ty;
      dst[doffb + (size_t)(j0 + r) * ldD + i0 + tx] = tile[tx][r];
    }
    return;
  }

  if (b < 8220){
    // -------- convert b1/b2/ce/wr tail (fp32 mode only) --------
    if (md) return;
    const size_t j = ((size_t)(b - 8192) * 256 + tid) * 4;  // 0..28668
    const float* src;
    const size_t doff = CO_B1 + j;
    if      (j < 4096)  src = (const float*)b1q + j;
    else if (j < 12288) src = (const float*)b2q + (j - 4096);
    else if (j < 20480) src = (const float*)cp + (j - 12288);
    else                src = (const float*)wp + (j - 20480);
    f32x4 v = *(const f32x4*)src;
    bf16x4 o;
    #pragma unroll
    for (int t = 0; t < 4; t++) o[t] = (__bf16)v[t];
    *(bf16x4*)(conv + doff) = o;
    return;
  }

  // -------- routing: 16 lanes/token, 16 tokens/block --------
  const int rb = b - 8220;               // 0..511
  const int g = tid >> 4, l = tid & 15;
  const int t = rb * 16 + g;

  if (tid < 8) hist[tid] = 0;
  // local centroid inv-norms (32KB read/block, L2-hot)
  {
    const int e = tid >> 5, i = tid & 31;
    float ss = 0.f;
    for (int j = 0; j < 32; j++){
      size_t d = (size_t)e * DM + i + j * 32;
      float v = md ? (float)((const __bf16*)cp)[d] : ((const float*)cp)[d];
      ss += v * v;
    }
    #pragma unroll
    for (int m = 1; m < 32; m <<= 1) ss += __shfl_xor(ss, m, 64);
    if (i == 0) cinvL[e] = 1.f / fmaxf(sqrtf(ss), 1e-12f);
  }
  __syncthreads();

  float xx = 0.f, cd[NE], wd[NE];
  #pragma unroll
  for (int e = 0; e < NE; e++){ cd[e] = 0.f; wd[e] = 0.f; }

  const size_t xbase = (size_t)t * DM;
  for (int j = 0; j < 16; j++){
    const int d0 = j * 64 + l * 4;
    f32x4 xv = ld4(xp, xbase + d0, md);
    if (!md){                            // fold x -> bf16 conversion in
      bf16x4 o;
      #pragma unroll
      for (int jj = 0; jj < 4; jj++) o[jj] = (__bf16)xv[jj];
      *(bf16x4*)(conv + CO_X + xbase + d0) = o;
    }
    xx += xv[0]*xv[0] + xv[1]*xv[1] + xv[2]*xv[2] + xv[3]*xv[3];
    #pragma unroll
    for (int e = 0; e < NE; e++){
      f32x4 cv = ld4(cp, (size_t)e * DM + d0, md);
      f32x4 wv = ld4(wp, (size_t)e * DM + d0, md);
      cd[e] += xv[0]*cv[0] + xv[1]*cv[1] + xv[2]*cv[2] + xv[3]*cv[3];
      wd[e] += xv[0]*wv[0] + xv[1]*wv[1] + xv[2]*wv[2] + xv[3]*wv[3];
    }
  }
  #pragma unroll
  for (int m = 1; m < 16; m <<= 1){
    xx += __shfl_xor(xx, m, 64);
    #pragma unroll
    for (int e = 0; e < NE; e++){
      cd[e] += __shfl_xor(cd[e], m, 64);
      wd[e] += __shfl_xor(wd[e], m, 64);
    }
  }

  if (l == 0){
    const float rxn = 1.f / fmaxf(sqrtf(xx), 1e-12f);
    float logits[NE];
    #pragma unroll
    for (int e = 0; e < NE; e++) logits[e] = cd[e] * rxn * cinvL[e] + wd[e];
    float m1 = -1e30f; int i1 = 0;
    #pragma unroll
    for (int e = 0; e < NE; e++) if (logits[e] > m1){ m1 = logits[e]; i1 = e; }
    float m2 = -1e30f; int i2 = (i1 == 0) ? 1 : 0;
    #pragma unroll
    for (int e = 0; e < NE; e++)
      if (e != i1 && logits[e] > m2){ m2 = logits[e]; i2 = e; }
    float denom = 0.f, ex1 = 0.f, ex2 = 0.f;
    #pragma unroll
    for (int e = 0; e < NE; e++){
      if (logits[e] >= m2){
        float ee = expf(logits[e] - m1);
        denom += ee;
        if (e == i1) ex1 = ee;
        if (e == i2) ex2 = ee;
      }
    }
    const float inv = 1.f / denom;
    gate2[t] = make_float2(ex1 * inv, ex2 * inv);
    top2[t] = i1 | (i2 << 8);
    atomicAdd(&hist[i1], 1);
    atomicAdd(&hist[i2], 1);
  }
  __syncthreads();
  if (tid < 8) b32[rb * 8 + tid] = hist[tid];  // own slot: no zero-init needed
  if (rb == 0 && tid == 0) meta[0] = md;
}

// ---- sched_k: fused offsets + place (1 block, 1024 thr) --------------------
// LDS Hillis-Steele scan over 512x8 per-block counts -> per-(rb,e) bases,
// then token placement via LDS cursors. Order within expert is irrelevant.
__global__ __launch_bounds__(1024) void sched_k(
    const int* __restrict__ top2, const float2* __restrict__ gate2,
    int* __restrict__ meta, const int* __restrict__ b32,
    int* __restrict__ tok, int* __restrict__ ae, float* __restrict__ agv,
    int* __restrict__ inv)
{
  __shared__ int bufA[4096];
  __shared__ int bufB[4096];
  __shared__ int offE[8];
  const int tid = threadIdx.x;

  for (int i = tid; i < 4096; i += 1024) bufA[i] = b32[i];
  __syncthreads();

  // inclusive scan along rb (512) for all 8 experts simultaneously
  int* cur = bufA; int* nxt = bufB;
  for (int d = 1; d < 512; d <<= 1){      // 9 iterations -> cur ends at bufB
    for (int i = tid; i < 4096; i += 1024){
      int v = cur[i];
      if ((i >> 3) >= d) v += cur[i - (d << 3)];
      nxt[i] = v;
    }
    __syncthreads();
    int* s = cur; cur = nxt; nxt = s;
  }

  if (tid == 0){
    int run = 0;
    #pragma unroll
    for (int e = 0; e < NE; e++){
      const int tt = cur[(511 << 3) + e];
      meta[16 + e] = tt; meta[32 + e] = run; offE[e] = run; run += tt;
    }
  }
  __syncthreads();

  // exclusive base per (rb,e): expert base + inclusive - own count
  for (int i = tid; i < 4096; i += 1024)
    nxt[i] = offE[i & 7] + cur[i] - b32[i];
  __syncthreads();

  for (int t = tid; t < T_TOK; t += 1024){
    const int p = top2[t];
    const float2 gg = gate2[t];
    const int rb = t >> 4;
    const int e1 = p & 255, e2 = (p >> 8) & 255;
    const int s1 = atomicAdd(&nxt[(rb << 3) + e1], 1);
    tok[s1] = t; ae[s1] = e1; agv[s1] = gg.x; inv[2 * t] = s1;
    const int s2 = atomicAdd(&nxt[(rb << 3) + e2], 1);
    tok[s2] = t; ae[s2] = e2; agv[s2] = gg.y; inv[2 * t + 1] = s2;
  }
}

// block -> (expert, 128-row tile)
__device__ __forceinline__ bool find_tile(const int* meta, int tm,
                                          int& e, int& base, int& valid)
{
  for (e = 0; e < NE; e++){
    const int cnt = meta[16 + e];
    const int nt = (cnt + 127) >> 7;
    if (tm < nt){
      const int r0 = tm << 7;
      base = meta[32 + e] + r0;
      valid = cnt - r0;
      return true;
    }
    tm -= nt;
  }
  return false;
}

// ---- grouped GEMM1 (R4 best: 128x128, BK=64, swizzled, 44.4us) -------------
// Hc = g * gelu(x @ w1_e + b1_e)
__global__ __launch_bounds__(512, 2) void gemm1g_k(
    const void* xq, const void* b1q, const __bf16* __restrict__ conv,
    const int* __restrict__ meta, const int* __restrict__ tok,
    const float* __restrict__ agv, __bf16* __restrict__ Hc)
{
  const int md = meta[0];
  const __bf16* X  = md ? (const __bf16*)xq : conv + CO_X;
  const __bf16* WT = conv + CO_W1;   // w1T [8][512][1024]
  const __bf16* bb = md ? (const __bf16*)b1q : conv + CO_B1;

  int e, base, valid;
  if (!find_tile(meta, blockIdx.x, e, base, valid)) return;
  const int n0 = blockIdx.y * 128;

  __shared__ __attribute__((aligned(16))) __bf16 As[2][128 * 64];  // 2x16KB
  __shared__ __attribute__((aligned(16))) __bf16 Bs[2][128 * 64];  // 2x16KB

  const int tid = threadIdx.x;
  const int wv = tid >> 6, lane = tid & 63;
  const int q = lane >> 4, ln = lane & 15;
  const int wm = (wv >> 2) * 64, wn = (wv & 3) * 32;   // 2x4 waves, 64x32 each
  const int swz = ln & 7;                               // read-side row XOR
  f32x4 acc[4][2] = {};

  const int srow = tid >> 3, sch = tid & 7;
  const int sx = ((sch ^ (srow & 7)) << 3);             // pre-swizzled k-offset
  const int ta = tok[base + ((srow      < valid) ? srow      : 0)];
  const int tb = tok[base + ((srow + 64 < valid) ? srow + 64 : 0)];
  const __bf16* Ag0 = X + (size_t)ta * DM + sx;
  const __bf16* Ag1 = X + (size_t)tb * DM + sx;
  const __bf16* Bg0 = WT + (size_t)e * (DE * DM) + (size_t)(n0 + srow) * DM + sx;
  const __bf16* Bg1 = Bg0 + (size_t)64 * DM;

  #define G1_STAGE(BUF, K0)                                   \
    do {                                                      \
      async_ld16(Ag0 + (K0), &As[BUF][tid * 8]);              \
      async_ld16(Ag1 + (K0), &As[BUF][tid * 8 + 4096]);       \
      async_ld16(Bg0 + (K0), &Bs[BUF][tid * 8]);              \
      async_ld16(Bg1 + (K0), &Bs[BUF][tid * 8 + 4096]);       \
    } while (0)

  #define G1_COMPUTE(BUF)                                                      \
    do {                                                                       \
      _Pragma("unroll")                                                        \
      for (int kk = 0; kk < 2; kk++){                                          \
        bf16x8 af[4], bfr[2];                                                  \
        const int ch = (((kk << 2) | q) ^ swz) << 3;                           \
        _Pragma("unroll")                                                      \
        for (int mi = 0; mi < 4; mi++)                                         \
          af[mi] = *(const bf16x8*)&As[BUF][(wm + mi * 16 + ln) * 64 + ch];    \
        _Pragma("unroll")                                                      \
        for (int ni = 0; ni < 2; ni++)                                         \
          bfr[ni] = *(const bf16x8*)&Bs[BUF][(wn + ni * 16 + ln) * 64 + ch];   \
        _Pragma("unroll")                                                      \
        for (int mi = 0; mi < 4; mi++)                                         \
          _Pragma("unroll")                                                    \
          for (int ni = 0; ni < 2; ni++)                                       \
            acc[mi][ni] = __builtin_amdgcn_mfma_f32_16x16x32_bf16(             \
                af[mi], bfr[ni], acc[mi][ni], 0, 0, 0);                        \
      }                                                                        \
    } while (0)

  G1_STAGE(0, 0);
  __syncthreads();
  int cr = 0;
  for (int t = 0; t < 16; ++t){
    if (t < 15) G1_STAGE(cr ^ 1, (t + 1) * 64);
    G1_COMPUTE(cr);
    __syncthreads();
    cr ^= 1;
  }
  #undef G1_STAGE
  #undef G1_COMPUTE

  const int coln = n0 + wn;
  float bset[2];
  #pragma unroll
  for (int ni = 0; ni < 2; ni++)
    bset[ni] = (float)bb[e * DE + coln + ni * 16 + ln];
  #pragma unroll
  for (int mi = 0; mi < 4; mi++){
    #pragma unroll
    for (int r = 0; r < 4; r++){
      const int row = wm + mi * 16 + q * 4 + r;
      if (row < valid){
        const int slot = base + row;
        const float g = agv[slot];
        #pragma unroll
        for (int ni = 0; ni < 2; ni++){
          float v = acc[mi][ni][r] + bset[ni];
          float h = 0.5f * v * (1.0f + erff(v * 0.70710678118654752f));
          Hc[(size_t)slot * DE + coln + ni * 16 + ln] = (__bf16)(g * h);
        }
      }
    }
  }
}

// ---- grouped GEMM2 (R0 best: 128x128, 256 thr, m97-style staging) ----------
// Oc = Hc @ w2_e
__global__ __launch_bounds__(256) void gemm2g_k(
    const __bf16* __restrict__ Hc, const __bf16* __restrict__ conv,
    const int* __restrict__ meta, __bf16* __restrict__ Oc)
{
  const __bf16* WT = conv + CO_W2;   // w2T [8][1024][512]

  int e, base, valid;
  if (!find_tile(meta, blockIdx.x, e, base, valid)) return;
  const int n0 = blockIdx.y * 128;

  __shared__ __attribute__((aligned(16))) __bf16 As[128 * 32];
  __shared__ __attribute__((aligned(16))) __bf16 Bs[128 * 32];

  const int tid = threadIdx.x;
  const int wv = tid >> 6, lane = tid & 63;
  const int q = lane >> 4, ln = lane & 15;
  const int wm = (wv >> 1) * 64, wn = (wv & 1) * 64;
  f32x4 acc[4][4] = {};

  const int sr = tid >> 2, sc = (tid & 3) * 8;
  const int r0 = (sr      < valid) ? sr      : 0;
  const int r1 = (sr + 64 < valid) ? sr + 64 : 0;
  const __bf16* Ag0 = Hc + (size_t)(base + r0) * DE + sc;
  const __bf16* Ag1 = Hc + (size_t)(base + r1) * DE + sc;
  const __bf16* Bg0 = WT + (size_t)e * (DM * DE) + (size_t)(n0 + sr) * DE + sc;
  const __bf16* Bg1 = Bg0 + (size_t)64 * DE;

  for (int k0 = 0; k0 < DE; k0 += 32){
    __syncthreads();
    async_ld16(Ag0 + k0, As + tid * 8);
    async_ld16(Ag1 + k0, As + 2048 + tid * 8);
    async_ld16(Bg0 + k0, Bs + tid * 8);
    async_ld16(Bg1 + k0, Bs + 2048 + tid * 8);
    __syncthreads();

    bf16x8 af[4], bfr[4];
    #pragma unroll
    for (int mi = 0; mi < 4; mi++)
      af[mi] = *(const bf16x8*)&As[(wm + mi * 16 + ln) * 32 + q * 8];
    #pragma unroll
    for (int ni = 0; ni < 4; ni++)
      bfr[ni] = *(const bf16x8*)&Bs[(wn + ni * 16 + ln) * 32 + q * 8];
    #pragma unroll
    for (int mi = 0; mi < 4; mi++)
      #pragma unroll
      for (int ni = 0; ni < 4; ni++)
        acc[mi][ni] = __builtin_amdgcn_mfma_f32_16x16x32_bf16(
            af[mi], bfr[ni], acc[mi][ni], 0, 0, 0);
  }

  #pragma unroll
  for (int mi = 0; mi < 4; mi++){
    #pragma unroll
    for (int r = 0; r < 4; r++){
      const int row = wm + mi * 16 + q * 4 + r;
      if (row < valid){
        const int slot = base + row;
        #pragma unroll
        for (int ni = 0; ni < 4; ni++)
          Oc[(size_t)slot * DM + n0 + wn + ni * 16 + ln] = (__bf16)acc[mi][ni][r];
      }
    }
  }
}

// ---- combine: out[t] = Oc[s1] + Oc[s2] + g1*b2[e1] + g2*b2[e2] -------------
__global__ __launch_bounds__(256) void combine_k(
    const __bf16* __restrict__ Oc, const int* __restrict__ inv,
    const int* __restrict__ ae, const float* __restrict__ agv,
    const void* b2q, const int* __restrict__ meta, void* out)
{
  const int md = meta[0];
  const int t = blockIdx.x;
  const int s1 = inv[2 * t], s2 = inv[2 * t + 1];
  const int e1 = ae[s1], e2 = ae[s2];
  const float g1 = agv[s1], g2 = agv[s2];
  const int c = threadIdx.x * 4;

  bf16x4 o1 = *(const bf16x4*)(Oc + (size_t)s1 * DM + c);
  bf16x4 o2 = *(const bf16x4*)(Oc + (size_t)s2 * DM + c);
  f32x4 bv1 = ld4(b2q, (size_t)e1 * DM + c, md);
  f32x4 bv2 = ld4(b2q, (size_t)e2 * DM + c, md);
  f32x4 rr;
  #pragma unroll
  for (int j = 0; j < 4; j++)
    rr[j] = (float)o1[j] + (float)o2[j] + g1 * bv1[j] + g2 * bv2[j];

  if (md){
    bf16x4 ob;
    #pragma unroll
    for (int j = 0; j < 4; j++) ob[j] = (__bf16)rr[j];
    *(bf16x4*)((__bf16*)out + (size_t)t * DM + c) = ob;
  } else {
    *(f32x4*)((float*)out + (size_t)t * DM + c) = rr;
  }
}

extern "C" void kernel_launch(void* const* d_in, const int* in_sizes, int n_in,
                              void* d_out, int out_size, void* d_ws, size_t ws_size,
                              hipStream_t stream)
{
  char* ws = (char*)d_ws;
  int*    meta  = (int*)ws;
  float2* gate2 = (float2*)(ws + WS_GATE2);
  int*    b32   = (int*)(ws + WS_B32);
  int*    top2  = (int*)(ws + WS_TOP2);
  int*    tok   = (int*)(ws + WS_TOK);
  int*    ae    = (int*)(ws + WS_AE);
  float*  agv   = (float*)(ws + WS_AG);
  int*    inv   = (int*)(ws + WS_INV);
  __bf16* conv  = (__bf16*)(ws + WS_CONV);
  __bf16* Hc    = (__bf16*)(ws + WS_HC);
  __bf16* Oc    = (__bf16*)(ws + WS_OC);

  // 5 launches (was 9): ~10us serialized overhead per launch was ~40% of total
  prep_k<<<8732, 256, 0, stream>>>(d_in[0], d_in[1], d_in[3], d_in[2],
                                   d_in[4], d_in[5], d_in[6],
                                   conv, meta, gate2, top2, b32);
  sched_k<<<1, 1024, 0, stream>>>(top2, gate2, meta, b32, tok, ae, agv, inv);
  gemm1g_k<<<dim3(136, 4), 512, 0, stream>>>(d_in[0], d_in[2], conv, meta,
                                             tok, agv, Hc);
  gemm2g_k<<<dim3(136, 8), 256, 0, stream>>>(Hc, conv, meta, Oc);
  combine_k<<<T_TOK, 256, 0, stream>>>(Oc, inv, ae, agv, d_in[4], meta, d_out);
}